// Round 3
// baseline (3774.962 us; speedup 1.0000x reference)
//
#include <hip/hip_runtime.h>

// out = (sum_k h[k] * S_k) @ x  — COO SpMM via coarse-bucket binning + LDS accumulation.
//
// Round-2 lesson: exact per-row sort scattered 8B stores across 100K active
// streams -> every edge paid a full random 64B HBM line (WRITE_SIZE ~500MB,
// 675us). Fix: bin into buckets of RPB=128 rows (NB=782 buckets) so the
// scatter appends to only 782 streams (L2-resident lines, full-line fills),
// and accumulate per-bucket in a 32KB LDS tile with ds_add_f32.
//
// Phases (no global f32 atomics, no global int atomics):
//   A) count:   per-WG LDS histogram over buckets -> cnt[b][g]
//   B) scan:    exclusive scan of cnt (b-major) -> offs;  offs[n]=KE
//   C) scatter: per-WG LDS cursors (from offs) -> payload {rl<<17|col, w}
//   D) spmv:    WG per bucket: gather x[col], ds_add into acc[128][64], store
//
// ws: cnt[NB*G] | offs[NB*G+1] | pad | payload[KE] (int2)

#define RPB    128          // rows per bucket
#define G_SCAT 256          // count/scatter workgroups
#define NB_MAX 1024

static __global__ __launch_bounds__(256) void count_kernel(
    const int* __restrict__ rows, int* __restrict__ cnt,
    int KE, int NB, int chunk)
{
    __shared__ int hist[NB_MAX];
    const int g = blockIdx.x;
    for (int j = threadIdx.x; j < NB; j += blockDim.x) hist[j] = 0;
    __syncthreads();
    const int lo = g * chunk;
    const int hi = min(lo + chunk, KE);
    for (int e = lo + threadIdx.x; e < hi; e += blockDim.x)
        atomicAdd(&hist[rows[e] >> 7], 1);
    __syncthreads();
    for (int j = threadIdx.x; j < NB; j += blockDim.x)
        cnt[(size_t)j * G_SCAT + g] = hist[j];
}

static __global__ __launch_bounds__(1024) void scan_kernel(
    const int* __restrict__ cnt, int* __restrict__ offs, int n)
{
    __shared__ int sums[1024];
    const int t = threadIdx.x;
    const int chunk = (n + 1023) >> 10;
    const int lo = t * chunk;
    const int hi = min(lo + chunk, n);
    int s = 0;
    for (int i = lo; i < hi; ++i) s += cnt[i];
    sums[t] = s;
    __syncthreads();
    for (int d = 1; d < 1024; d <<= 1) {
        int v = (t >= d) ? sums[t - d] : 0;
        __syncthreads();
        sums[t] += v;
        __syncthreads();
    }
    int run = (t > 0) ? sums[t - 1] : 0;
    for (int i = lo; i < hi; ++i) {
        int cv = cnt[i];
        offs[i] = run;
        run += cv;
    }
    if (t == 1023) offs[n] = sums[1023];
}

static __global__ __launch_bounds__(256) void scatter_kernel(
    const int*   __restrict__ rows,
    const int*   __restrict__ cols,
    const float* __restrict__ vals,
    const float* __restrict__ h,
    const int*   __restrict__ offs,
    int2*        __restrict__ payload,
    int KE, int E, int K, int NB, int chunk)
{
    __shared__ int lcur[NB_MAX];
    const int g = blockIdx.x;
    for (int j = threadIdx.x; j < NB; j += blockDim.x)
        lcur[j] = offs[(size_t)j * G_SCAT + g];
    __syncthreads();
    const int lo = g * chunk;
    const int hi = min(lo + chunk, KE);
    if (lo >= hi) return;
    const int k0 = lo / E;
    const int k1 = min((hi - 1) / E, K - 1);
    for (int k = k0; k <= k1; ++k) {
        const float hk = h[k];
        const int s = max(lo, k * E);
        const int t = min(hi, (k + 1) * E);
        for (int e = s + threadIdx.x; e < t; e += blockDim.x) {
            const int r = rows[e];
            const int pos = atomicAdd(&lcur[r >> 7], 1);
            payload[pos] = make_int2(((r & (RPB - 1)) << 17) | cols[e],
                                     __float_as_int(hk * vals[e]));
        }
    }
}

static __global__ __launch_bounds__(512) void spmv_kernel(
    const int*  __restrict__ offs,
    const int2* __restrict__ payload,
    const float* __restrict__ x,
    float*       __restrict__ out,
    int N, int NB)
{
    extern __shared__ float acc[];           // RPB*64 floats = 32KB
    const int b = blockIdx.x;
    for (int i = threadIdx.x; i < RPB * 64; i += blockDim.x) acc[i] = 0.f;
    __syncthreads();

    const int bs = offs[(size_t)b * G_SCAT];
    const int be = offs[(size_t)(b + 1) * G_SCAT];   // b=NB-1 hits offs[n]=KE
    const int lane = threadIdx.x & 63;
    const int wv   = threadIdx.x >> 6;
    const int nwv  = blockDim.x >> 6;

    int e = bs + wv;
    for (; e + nwv < be; e += 2 * nwv) {             // unroll 2 for MLP
        const int2 p0 = payload[e];
        const int2 p1 = payload[e + nwv];
        const float xv0 = x[(size_t)(p0.x & 0x1FFFF) * 64 + lane];
        const float xv1 = x[(size_t)(p1.x & 0x1FFFF) * 64 + lane];
        atomicAdd(&acc[(p0.x >> 17) * 64 + lane], __int_as_float(p0.y) * xv0);
        atomicAdd(&acc[(p1.x >> 17) * 64 + lane], __int_as_float(p1.y) * xv1);
    }
    if (e < be) {
        const int2 p = payload[e];
        const float xv = x[(size_t)(p.x & 0x1FFFF) * 64 + lane];
        atomicAdd(&acc[(p.x >> 17) * 64 + lane], __int_as_float(p.y) * xv);
    }
    __syncthreads();

    const int base = b * RPB;
    const int n0 = min(RPB, N - base);
    for (int i = threadIdx.x; i < n0 * 64; i += blockDim.x)
        out[(size_t)base * 64 + i] = acc[i];
}

// Round-1 fallback (atomic scatter) if ws is too small.
static __global__ __launch_bounds__(256) void gtconv_scatter(
    const float* __restrict__ x, const float* __restrict__ h,
    const float* __restrict__ vals, const int* __restrict__ rows,
    const int* __restrict__ cols, float* __restrict__ out, int KE, int E)
{
    const int lane = threadIdx.x & 63;
    int wave = (blockIdx.x * blockDim.x + threadIdx.x) >> 6;
    const int nwaves = (gridDim.x * blockDim.x) >> 6;
    for (int e = wave; e < KE; e += nwaves) {
        float w = h[e / E] * vals[e];
        float xv = x[(size_t)cols[e] * 64 + lane];
        unsafeAtomicAdd(&out[(size_t)rows[e] * 64 + lane], xv * w);
    }
}

extern "C" void kernel_launch(void* const* d_in, const int* in_sizes, int n_in,
                              void* d_out, int out_size, void* d_ws, size_t ws_size,
                              hipStream_t stream) {
    const float* x    = (const float*)d_in[0];
    const float* h    = (const float*)d_in[1];
    const float* vals = (const float*)d_in[2];
    const int*   rows = (const int*)d_in[3];
    const int*   cols = (const int*)d_in[4];
    float* out = (float*)d_out;

    const int K  = in_sizes[1];
    const int KE = in_sizes[2];
    const int E  = KE / K;
    const int F  = 64;
    const int N  = in_sizes[0] / F;
    const int NB = (N + RPB - 1) / RPB;

    const size_t NBG     = (size_t)NB * G_SCAT;
    const size_t cnt_off  = 0;
    const size_t offs_off = cnt_off + NBG * 4;
    const size_t pl_off   = (offs_off + (NBG + 1) * 4 + 7) & ~(size_t)7;
    const size_t need     = pl_off + (size_t)KE * 8;

    if (ws_size < need || NB > NB_MAX) {
        hipMemsetAsync(out, 0, (size_t)out_size * sizeof(float), stream);
        gtconv_scatter<<<8192, 256, 0, stream>>>(x, h, vals, rows, cols, out, KE, E);
        return;
    }

    char* ws = (char*)d_ws;
    int*  cnt     = (int*)(ws + cnt_off);
    int*  offs    = (int*)(ws + offs_off);
    int2* payload = (int2*)(ws + pl_off);

    const int chunk = (KE + G_SCAT - 1) / G_SCAT;

    count_kernel<<<G_SCAT, 256, 0, stream>>>(rows, cnt, KE, NB, chunk);
    scan_kernel<<<1, 1024, 0, stream>>>(cnt, offs, (int)NBG);
    scatter_kernel<<<G_SCAT, 256, 0, stream>>>(rows, cols, vals, h, offs,
                                               payload, KE, E, K, NB, chunk);
    spmv_kernel<<<NB, 512, RPB * 64 * sizeof(float), stream>>>(
        offs, payload, x, out, N, NB);
}

// Round 4
// 560.427 us; speedup vs baseline: 6.7359x; 6.7359x over previous
//
#include <hip/hip_runtime.h>
#include <hip/hip_bf16.h>

// out = (sum_k h[k] * S_k) @ x  — COO SpMM, bucket-binned, ATOMIC-FREE accumulate.
//
// Round-3 lesson: shared-float atomicAdd in the accumulate phase ran at
// ~258 cy/edge (3353us) — likely a CAS loop, definitely serial. Fix:
// sub-bin each 64-row bucket by (row&3) into 4 disjoint streams; wave wv
// of an spmv block exclusively owns rows rl%4==wv, so the LDS accumulate
// is plain ds_read+fma+ds_write. 8-deep gather pipeline, 1563 blocks.
//
// Phases:
//   A) count:  per-WG LDS histogram over 6252 streams -> cnt[s][g]
//   B) scan:   3-step hierarchical exclusive scan (in place) -> offsets
//   C) scatter: per-WG LDS cursors -> pidx {rl<<17|col} + pw {bf16 w}
//   D) spmv:   block per bucket, wave per row-class, reg/LDS accumulate
//
// ws: cnt[NSTREAM*GWG] | ssBeg[NSTREAM+1] | pidx[KE] | pw[KE] (~54.5MB)

#define RPB   64           // rows per bucket
#define SUB   4            // row classes (= waves per spmv block)
#define GWG   256          // count/scatter workgroups

static __global__ __launch_bounds__(1024) void count_kernel(
    const int* __restrict__ rows, int* __restrict__ cnt,
    int KE, int NSTREAM, int chunk)
{
    extern __shared__ int hist[];              // NSTREAM ints
    const int g = blockIdx.x;
    for (int j = threadIdx.x; j < NSTREAM; j += blockDim.x) hist[j] = 0;
    __syncthreads();
    const int lo = g * chunk;
    const int hi = min(lo + chunk, KE);
    for (int e = lo + threadIdx.x; e < hi; e += blockDim.x) {
        const int r = rows[e];
        atomicAdd(&hist[((r >> 6) << 2) | (r & 3)], 1);   // int LDS atomic: native
    }
    __syncthreads();
    for (int j = threadIdx.x; j < NSTREAM; j += blockDim.x)
        cnt[(size_t)j * GWG + g] = hist[j];
}

// B1: per-stream exclusive scan of its GWG counts (in place); total -> ssBeg[s]
static __global__ __launch_bounds__(GWG) void scan1_kernel(
    int* __restrict__ cnt, int* __restrict__ ssBeg)
{
    __shared__ int tmp[GWG];
    const int s = blockIdx.x;
    const int t = threadIdx.x;
    const int v = cnt[(size_t)s * GWG + t];
    tmp[t] = v;
    __syncthreads();
    for (int d = 1; d < GWG; d <<= 1) {
        int u = (t >= d) ? tmp[t - d] : 0;
        __syncthreads();
        tmp[t] += u;
        __syncthreads();
    }
    cnt[(size_t)s * GWG + t] = tmp[t] - v;     // exclusive
    if (t == GWG - 1) ssBeg[s] = tmp[t];       // stream total
}

// B2: exclusive scan of ssBeg[0..n) in place; ssBeg[n] = grand total
static __global__ __launch_bounds__(1024) void scan2_kernel(
    int* __restrict__ a, int n)
{
    __shared__ int sums[1024];
    const int t = threadIdx.x;
    const int chunk = (n + 1023) >> 10;
    const int lo = t * chunk;
    const int hi = min(lo + chunk, n);
    int s = 0;
    for (int i = lo; i < hi; ++i) s += a[i];
    sums[t] = s;
    __syncthreads();
    for (int d = 1; d < 1024; d <<= 1) {
        int v = (t >= d) ? sums[t - d] : 0;
        __syncthreads();
        sums[t] += v;
        __syncthreads();
    }
    int run = (t > 0) ? sums[t - 1] : 0;
    for (int i = lo; i < hi; ++i) {
        const int cv = a[i];
        a[i] = run;
        run += cv;
    }
    if (t == 1023) a[n] = sums[1023];
}

// B3: cnt[s][g] += stream base
static __global__ __launch_bounds__(1024) void scan3_kernel(
    int* __restrict__ cnt, const int* __restrict__ ssBeg, int total)
{
    const int i = blockIdx.x * blockDim.x + threadIdx.x;
    if (i < total) cnt[i] += ssBeg[i >> 8];    // i / GWG
}

static __global__ __launch_bounds__(1024) void scatter_kernel(
    const int*   __restrict__ rows,
    const int*   __restrict__ cols,
    const float* __restrict__ vals,
    const float* __restrict__ h,
    const int*   __restrict__ cnt,
    int*            __restrict__ pidx,
    __hip_bfloat16* __restrict__ pw,
    int KE, int E, int K, int NSTREAM, int chunk)
{
    extern __shared__ int lcur[];              // NSTREAM cursors
    const int g = blockIdx.x;
    for (int j = threadIdx.x; j < NSTREAM; j += blockDim.x)
        lcur[j] = cnt[(size_t)j * GWG + g];
    __syncthreads();
    const int lo = g * chunk;
    const int hi = min(lo + chunk, KE);
    if (lo >= hi) return;
    const int k0 = lo / E;
    const int k1 = min((hi - 1) / E, K - 1);
    for (int k = k0; k <= k1; ++k) {
        const float hk = h[k];
        const int s0 = max(lo, k * E);
        const int s1 = min(hi, (k + 1) * E);
        for (int e = s0 + threadIdx.x; e < s1; e += blockDim.x) {
            const int r = rows[e];
            const int st = ((r >> 6) << 2) | (r & 3);
            const int pos = atomicAdd(&lcur[st], 1);      // int LDS atomic
            pidx[pos] = ((r & 63) << 17) | cols[e];
            pw[pos]   = __float2bfloat16(hk * vals[e]);
        }
    }
}

static __global__ __launch_bounds__(256) void spmv_kernel(
    const int*            __restrict__ ssBeg,
    const int*            __restrict__ pidx,
    const __hip_bfloat16* __restrict__ pw,
    const float*          __restrict__ x,
    float*                __restrict__ out,
    int N)
{
    __shared__ float acc[RPB * 64];            // 16KB
    const int b = blockIdx.x;
    for (int i = threadIdx.x; i < RPB * 64; i += 256) acc[i] = 0.f;
    __syncthreads();

    const int lane = threadIdx.x & 63;
    const int wv   = threadIdx.x >> 6;
    const int s    = b * SUB + wv;
    int e       = ssBeg[s];
    const int be = ssBeg[s + 1];

    // 8 edges per iteration, all 8 gathers in flight before the LDS RMWs.
    while (e + 8 <= be) {
        int ia[4], ib[4];
        float wa[4], wb[4], xa[4], xb[4];
        #pragma unroll
        for (int j = 0; j < 4; ++j) {
            ia[j] = pidx[e + j];
            wa[j] = __bfloat162float(pw[e + j]);
        }
        #pragma unroll
        for (int j = 0; j < 4; ++j) {
            ib[j] = pidx[e + 4 + j];
            wb[j] = __bfloat162float(pw[e + 4 + j]);
        }
        #pragma unroll
        for (int j = 0; j < 4; ++j)
            xa[j] = x[(size_t)(ia[j] & 0x1FFFF) * 64 + lane];
        #pragma unroll
        for (int j = 0; j < 4; ++j)
            xb[j] = x[(size_t)(ib[j] & 0x1FFFF) * 64 + lane];
        #pragma unroll
        for (int j = 0; j < 4; ++j)
            acc[(ia[j] >> 17) * 64 + lane] += wa[j] * xa[j];   // wave-exclusive rows
        #pragma unroll
        for (int j = 0; j < 4; ++j)
            acc[(ib[j] >> 17) * 64 + lane] += wb[j] * xb[j];
        e += 8;
    }
    for (; e < be; ++e) {
        const int i_ = pidx[e];
        const float w_ = __bfloat162float(pw[e]);
        acc[(i_ >> 17) * 64 + lane] += w_ * x[(size_t)(i_ & 0x1FFFF) * 64 + lane];
    }
    __syncthreads();

    const int base = b * RPB;
    const int nrow = min(RPB, N - base);
    for (int i = threadIdx.x; i < nrow * 64; i += 256)
        out[(size_t)base * 64 + i] = acc[i];
}

// Round-1 fallback (atomic scatter) if ws is too small.
static __global__ __launch_bounds__(256) void gtconv_scatter(
    const float* __restrict__ x, const float* __restrict__ h,
    const float* __restrict__ vals, const int* __restrict__ rows,
    const int* __restrict__ cols, float* __restrict__ out, int KE, int E)
{
    const int lane = threadIdx.x & 63;
    int wave = (blockIdx.x * blockDim.x + threadIdx.x) >> 6;
    const int nwaves = (gridDim.x * blockDim.x) >> 6;
    for (int e = wave; e < KE; e += nwaves) {
        float w = h[e / E] * vals[e];
        float xv = x[(size_t)cols[e] * 64 + lane];
        unsafeAtomicAdd(&out[(size_t)rows[e] * 64 + lane], xv * w);
    }
}

extern "C" void kernel_launch(void* const* d_in, const int* in_sizes, int n_in,
                              void* d_out, int out_size, void* d_ws, size_t ws_size,
                              hipStream_t stream) {
    const float* x    = (const float*)d_in[0];
    const float* h    = (const float*)d_in[1];
    const float* vals = (const float*)d_in[2];
    const int*   rows = (const int*)d_in[3];
    const int*   cols = (const int*)d_in[4];
    float* out = (float*)d_out;

    const int K  = in_sizes[1];
    const int KE = in_sizes[2];
    const int E  = KE / K;
    const int F  = 64;
    const int N  = in_sizes[0] / F;
    const int NB      = (N + RPB - 1) / RPB;       // 1563
    const int NSTREAM = NB * SUB;                  // 6252

    const size_t lds_need = (size_t)NSTREAM * 4;   // count/scatter LDS
    const size_t cnt_off  = 0;
    const size_t cnt_sz   = (size_t)NSTREAM * GWG * 4;
    const size_t ss_off   = cnt_off + cnt_sz;
    const size_t ss_sz    = (size_t)(NSTREAM + 1) * 4;
    const size_t pidx_off = (ss_off + ss_sz + 15) & ~(size_t)15;
    const size_t pw_off   = pidx_off + (size_t)KE * 4;
    const size_t need     = pw_off + (size_t)KE * 2;

    if (ws_size < need || lds_need > 64 * 1024) {
        hipMemsetAsync(out, 0, (size_t)out_size * sizeof(float), stream);
        gtconv_scatter<<<8192, 256, 0, stream>>>(x, h, vals, rows, cols, out, KE, E);
        return;
    }

    char* ws = (char*)d_ws;
    int*            cnt   = (int*)(ws + cnt_off);
    int*            ssBeg = (int*)(ws + ss_off);
    int*            pidx  = (int*)(ws + pidx_off);
    __hip_bfloat16* pw    = (__hip_bfloat16*)(ws + pw_off);

    const int chunk = (KE + GWG - 1) / GWG;

    count_kernel<<<GWG, 1024, lds_need, stream>>>(rows, cnt, KE, NSTREAM, chunk);
    scan1_kernel<<<NSTREAM, GWG, 0, stream>>>(cnt, ssBeg);
    scan2_kernel<<<1, 1024, 0, stream>>>(ssBeg, NSTREAM);
    const int total = NSTREAM * GWG;
    scan3_kernel<<<(total + 1023) / 1024, 1024, 0, stream>>>(cnt, ssBeg, total);
    scatter_kernel<<<GWG, 1024, lds_need, stream>>>(rows, cols, vals, h, cnt,
                                                    pidx, pw, KE, E, K, NSTREAM, chunk);
    spmv_kernel<<<NB, 256, 0, stream>>>(ssBeg, pidx, pw, x, out, N);
}

// Round 5
// 407.591 us; speedup vs baseline: 9.2616x; 1.3750x over previous
//
#include <hip/hip_runtime.h>

// out = (sum_k h[k] * S_k) @ x  — COO SpMM, bucket-binned, atomic-free accumulate.
//
// Round-4 lesson: scatter with 6252 streams x 256 WGs = 1.6M concurrent
// partial-line write positions (12.8MB/XCD vs 4MB L2) -> every 8B payload
// store paid a full 64B HBM line (WRITE_SIZE ~500MB, 390us). Fix: SUB=2
// (NSTREAM=3126) and G=128 WGs -> 3126*16*64B = 3.2MB active lines per XCD
// -> L2-resident until full -> payload streams out at its true 64MB size.
// Payload back to one int2 {(rl<<17)|col, f32 w} = single 8B store/edge.
//
// spmv: block per 64-row bucket, 2 waves; wave wv exclusively owns rows
// r%2==wv -> plain ds_read+fma+ds_write accumulate, 16-deep gather pipeline.
//
// ws: cnt[NSTREAM*G] | ssBeg[NSTREAM+1] | pad | payload[KE] (int2)  (~65.6MB)

#define RPB   64           // rows per bucket
#define SUB   2            // row classes (= waves per spmv block)
#define GWG   128          // count/scatter workgroups

static __global__ __launch_bounds__(1024) void count_kernel(
    const int* __restrict__ rows, int* __restrict__ cnt,
    int KE, int NSTREAM, int chunk)
{
    extern __shared__ int hist[];              // NSTREAM ints
    const int g = blockIdx.x;
    for (int j = threadIdx.x; j < NSTREAM; j += blockDim.x) hist[j] = 0;
    __syncthreads();
    const int lo = g * chunk;
    const int hi = min(lo + chunk, KE);
    for (int e = lo + threadIdx.x; e < hi; e += blockDim.x) {
        const int r = rows[e];
        atomicAdd(&hist[((r >> 6) << 1) | (r & 1)], 1);
    }
    __syncthreads();
    for (int j = threadIdx.x; j < NSTREAM; j += blockDim.x)
        cnt[(size_t)j * GWG + g] = hist[j];
}

// B1: per-stream exclusive scan of its GWG counts (in place); total -> ssBeg[s]
static __global__ __launch_bounds__(GWG) void scan1_kernel(
    int* __restrict__ cnt, int* __restrict__ ssBeg)
{
    __shared__ int tmp[GWG];
    const int s = blockIdx.x;
    const int t = threadIdx.x;
    const int v = cnt[(size_t)s * GWG + t];
    tmp[t] = v;
    __syncthreads();
    for (int d = 1; d < GWG; d <<= 1) {
        int u = (t >= d) ? tmp[t - d] : 0;
        __syncthreads();
        tmp[t] += u;
        __syncthreads();
    }
    cnt[(size_t)s * GWG + t] = tmp[t] - v;     // exclusive
    if (t == GWG - 1) ssBeg[s] = tmp[t];       // stream total
}

// B2: exclusive scan of ssBeg[0..n) in place; ssBeg[n] = grand total
static __global__ __launch_bounds__(1024) void scan2_kernel(
    int* __restrict__ a, int n)
{
    __shared__ int sums[1024];
    const int t = threadIdx.x;
    const int chunk = (n + 1023) >> 10;
    const int lo = t * chunk;
    const int hi = min(lo + chunk, n);
    int s = 0;
    for (int i = lo; i < hi; ++i) s += a[i];
    sums[t] = s;
    __syncthreads();
    for (int d = 1; d < 1024; d <<= 1) {
        int v = (t >= d) ? sums[t - d] : 0;
        __syncthreads();
        sums[t] += v;
        __syncthreads();
    }
    int run = (t > 0) ? sums[t - 1] : 0;
    for (int i = lo; i < hi; ++i) {
        const int cv = a[i];
        a[i] = run;
        run += cv;
    }
    if (t == 1023) a[n] = sums[1023];
}

// B3: cnt[s][g] += stream base
static __global__ __launch_bounds__(1024) void scan3_kernel(
    int* __restrict__ cnt, const int* __restrict__ ssBeg, int total)
{
    const int i = blockIdx.x * blockDim.x + threadIdx.x;
    if (i < total) cnt[i] += ssBeg[i >> 7];    // i / GWG (GWG=128)
}

static __global__ __launch_bounds__(1024) void scatter_kernel(
    const int*   __restrict__ rows,
    const int*   __restrict__ cols,
    const float* __restrict__ vals,
    const float* __restrict__ h,
    const int*   __restrict__ cnt,
    int2*        __restrict__ payload,
    int KE, int E, int K, int NSTREAM, int chunk)
{
    extern __shared__ int lcur[];              // NSTREAM cursors
    const int g = blockIdx.x;
    for (int j = threadIdx.x; j < NSTREAM; j += blockDim.x)
        lcur[j] = cnt[(size_t)j * GWG + g];
    __syncthreads();
    const int lo = g * chunk;
    const int hi = min(lo + chunk, KE);
    if (lo >= hi) return;
    const int k0 = lo / E;
    const int k1 = min((hi - 1) / E, K - 1);
    for (int k = k0; k <= k1; ++k) {
        const float hk = h[k];
        const int s0 = max(lo, k * E);
        const int s1 = min(hi, (k + 1) * E);
        for (int e = s0 + threadIdx.x; e < s1; e += blockDim.x) {
            const int r = rows[e];
            const int st = ((r >> 6) << 1) | (r & 1);
            const int pos = atomicAdd(&lcur[st], 1);      // int LDS atomic
            payload[pos] = make_int2(((r & 63) << 17) | cols[e],
                                     __float_as_int(hk * vals[e]));
        }
    }
}

static __global__ __launch_bounds__(128) void spmv_kernel(
    const int*  __restrict__ ssBeg,
    const int2* __restrict__ payload,
    const float* __restrict__ x,
    float*       __restrict__ out,
    int N)
{
    __shared__ float acc[RPB * 64];            // 16KB
    const int b = blockIdx.x;
    for (int i = threadIdx.x; i < RPB * 64; i += 128) acc[i] = 0.f;
    __syncthreads();

    const int lane = threadIdx.x & 63;
    const int wv   = threadIdx.x >> 6;         // 0..1, owns rows r%2==wv
    const int s    = b * SUB + wv;
    int e        = ssBeg[s];
    const int be = ssBeg[s + 1];

    // 16 edges per iteration: all 16 payload loads + 16 gathers in flight
    // before the (wave-exclusive, hazard-free) LDS read-modify-writes.
    while (e + 16 <= be) {
        int2 pa[8], pb[8];
        float xa[8], xb[8];
        #pragma unroll
        for (int j = 0; j < 8; ++j) pa[j] = payload[e + j];
        #pragma unroll
        for (int j = 0; j < 8; ++j) pb[j] = payload[e + 8 + j];
        #pragma unroll
        for (int j = 0; j < 8; ++j)
            xa[j] = x[(size_t)(pa[j].x & 0x1FFFF) * 64 + lane];
        #pragma unroll
        for (int j = 0; j < 8; ++j)
            xb[j] = x[(size_t)(pb[j].x & 0x1FFFF) * 64 + lane];
        #pragma unroll
        for (int j = 0; j < 8; ++j)
            acc[(pa[j].x >> 17) * 64 + lane] += __int_as_float(pa[j].y) * xa[j];
        #pragma unroll
        for (int j = 0; j < 8; ++j)
            acc[(pb[j].x >> 17) * 64 + lane] += __int_as_float(pb[j].y) * xb[j];
        e += 16;
    }
    for (; e < be; ++e) {
        const int2 p = payload[e];
        acc[(p.x >> 17) * 64 + lane] +=
            __int_as_float(p.y) * x[(size_t)(p.x & 0x1FFFF) * 64 + lane];
    }
    __syncthreads();

    const int base = b * RPB;
    const int nrow = min(RPB, N - base);
    for (int i = threadIdx.x; i < nrow * 64; i += 128)
        out[(size_t)base * 64 + i] = acc[i];
}

// Round-1 fallback (atomic scatter) if ws is too small.
static __global__ __launch_bounds__(256) void gtconv_scatter(
    const float* __restrict__ x, const float* __restrict__ h,
    const float* __restrict__ vals, const int* __restrict__ rows,
    const int* __restrict__ cols, float* __restrict__ out, int KE, int E)
{
    const int lane = threadIdx.x & 63;
    int wave = (blockIdx.x * blockDim.x + threadIdx.x) >> 6;
    const int nwaves = (gridDim.x * blockDim.x) >> 6;
    for (int e = wave; e < KE; e += nwaves) {
        float w = h[e / E] * vals[e];
        float xv = x[(size_t)cols[e] * 64 + lane];
        unsafeAtomicAdd(&out[(size_t)rows[e] * 64 + lane], xv * w);
    }
}

extern "C" void kernel_launch(void* const* d_in, const int* in_sizes, int n_in,
                              void* d_out, int out_size, void* d_ws, size_t ws_size,
                              hipStream_t stream) {
    const float* x    = (const float*)d_in[0];
    const float* h    = (const float*)d_in[1];
    const float* vals = (const float*)d_in[2];
    const int*   rows = (const int*)d_in[3];
    const int*   cols = (const int*)d_in[4];
    float* out = (float*)d_out;

    const int K  = in_sizes[1];
    const int KE = in_sizes[2];
    const int E  = KE / K;
    const int F  = 64;
    const int N  = in_sizes[0] / F;
    const int NB      = (N + RPB - 1) / RPB;       // 1563
    const int NSTREAM = NB * SUB;                  // 3126

    const size_t lds_need = (size_t)NSTREAM * 4;   // count/scatter LDS
    const size_t cnt_off  = 0;
    const size_t cnt_sz   = (size_t)NSTREAM * GWG * 4;
    const size_t ss_off   = cnt_off + cnt_sz;
    const size_t ss_sz    = (size_t)(NSTREAM + 1) * 4;
    const size_t pl_off   = (ss_off + ss_sz + 15) & ~(size_t)15;
    const size_t need     = pl_off + (size_t)KE * 8;

    if (ws_size < need || lds_need > 64 * 1024) {
        hipMemsetAsync(out, 0, (size_t)out_size * sizeof(float), stream);
        gtconv_scatter<<<8192, 256, 0, stream>>>(x, h, vals, rows, cols, out, KE, E);
        return;
    }

    char* ws = (char*)d_ws;
    int*  cnt     = (int*)(ws + cnt_off);
    int*  ssBeg   = (int*)(ws + ss_off);
    int2* payload = (int2*)(ws + pl_off);

    const int chunk = (KE + GWG - 1) / GWG;

    count_kernel<<<GWG, 1024, lds_need, stream>>>(rows, cnt, KE, NSTREAM, chunk);
    scan1_kernel<<<NSTREAM, GWG, 0, stream>>>(cnt, ssBeg);
    scan2_kernel<<<1, 1024, 0, stream>>>(ssBeg, NSTREAM);
    const int total = NSTREAM * GWG;
    scan3_kernel<<<(total + 1023) / 1024, 1024, 0, stream>>>(cnt, ssBeg, total);
    scatter_kernel<<<GWG, 1024, lds_need, stream>>>(rows, cols, vals, h, cnt,
                                                    payload, KE, E, K, NSTREAM, chunk);
    spmv_kernel<<<NB, 128, 0, stream>>>(ssBeg, payload, x, out, N);
}